// Round 8
// baseline (77.958 us; speedup 1.0000x reference)
//
#include <hip/hip_runtime.h>
#include <math.h>

#define HI 240
#define WI 135
#define NPIX (HI * WI)          // 32400
#define NF 1000
#define NCHUNK 20
#define FCHUNK (NF / NCHUNK)    // 50  (<= 64: single ballot round)
#define BLK 256
#define FREC 4                  // float4 per eval record
#define TW 8                    // tile width (px)
#define TH 8                    // tile height (px)
#define TX_N 17                 // ceil(135/8)
#define TY_N 30                 // 240/8
#define NTILE (TX_N * TY_N)     // 510
#define TPB 4                   // tiles (waves) per block
#define NBX ((NTILE + TPB - 1) / TPB)   // 128

#define CH_EVAL (FCHUNK * FREC)         // 200 float4 per chunk (eval AoS)
#define NSCAN 20                        // floats per face in scan SoA
#define CH_SCAN_F (NSCAN * FCHUNK)      // 1000 floats per chunk
#define CH_SCAN_V (CH_SCAN_F / 4)       // 250 float4 per chunk

// Eval record (4 x float4), read via wave-uniform LDS broadcast:
//   r0 = (p0x,p0y,e0x,e0y)  r1 = (p1x,p1y,e1x,e1y)  r2 = (p2x,p2y,e2x,e2y)
//   r3 = (rden0, rden1, rden2, tz_valid)
// Scan SoA (per chunk, arrays of FCHUNK floats; 4 B stride -> conflict-free
// lane gather). Array index k:
//   0 bx0, 1 by0, 2 bx1, 3 by1, 4 flag,
//   5..7 Px[k], 8..10 Py[k], 11..13 Ex[k] (orientation-signed),
//   14..16 Ey[k], 17..19 Rd[k]

__device__ __forceinline__ void project(float x, float y, float z,
                                        float& px, float& py) {
#pragma clang fp contract(off)
    // Bitwise-mirrors ref: z=max(v_z,1e-6); px=(1000*(-x)/z + 512)/1024*W; etc.
    float zc = fmaxf(z, 1e-6f);
    px = ((1000.0f * (-x)) / zc + 512.0f) / 1024.0f * (float)WI;
    py = ((1000.0f * (-y)) / zc + 512.0f) / 1024.0f * (float)HI;
}

// prep: compute all face records ONCE (R8 — replaces per-block recompute
// staging whose dependent gather+divide chain was the suspected sil floor).
__global__ __launch_bounds__(BLK) void prep_kernel(
    const float* __restrict__ verts, const int* __restrict__ faces,
    float* __restrict__ out, float4* __restrict__ gA, float* __restrict__ gS)
{
#pragma clang fp contract(off)
    int g = blockIdx.x * BLK + threadIdx.x;
    if (g == 0) out[0] = 0.0f;   // fin's atomicAdd target (harness poisons 0xAA)
    if (g >= NF) return;

    int i0 = faces[3 * g + 0], i1 = faces[3 * g + 1], i2 = faces[3 * g + 2];
    float x0 = verts[3 * i0 + 0], y0 = verts[3 * i0 + 1], z0 = verts[3 * i0 + 2];
    float x1 = verts[3 * i1 + 0], y1 = verts[3 * i1 + 1], z1 = verts[3 * i1 + 2];
    float x2 = verts[3 * i2 + 0], y2 = verts[3 * i2 + 1], z2 = verts[3 * i2 + 2];

    float p0x, p0y, p1x, p1y, p2x, p2y;
    project(x0, y0, z0, p0x, p0y);
    project(x1, y1, z1, p1x, p1y);
    project(x2, y2, z2, p2x, p2y);

    float e0x = p1x - p0x, e0y = p1y - p0y;
    float e1x = p2x - p1x, e1y = p2y - p1y;
    float e2x = p0x - p2x, e2y = p0y - p2y;
    float den0 = (e0x * e0x + e0y * e0y) + 1e-12f;
    float den1 = (e1x * e1x + e1y * e1y) + 1e-12f;
    float den2 = (e2x * e2x + e2y * e2y) + 1e-12f;
    float rd0 = 1.0f / den0, rd1 = 1.0f / den1, rd2 = 1.0f / den2;

    float tz = ((z0 + z1) + z2) / 3.0f;
    bool tzok = tz > 1e-6f;

    // Pathology rule (provable): fp cross sign flip outside bbox+0.3px needs
    // two simultaneously-ambiguous crosses; safe iff area2 >= 4e-3*lmax^2
    // and lmax <= 2000px. Unsafe faces: infinite bbox, no SAT cull.
    float orient = e0x * e1y - e0y * e1x;   // 2*signed area
    float area2 = fabsf(orient);
    float l2max = fmaxf(den0, fmaxf(den1, den2));
    bool dup = (i0 == i1) || (i1 == i2) || (i2 == i0);
    bool patho = dup || (area2 < 4.0e-3f * l2max) || (l2max > 4.0e6f);

    float bx0, by0, bx1, by1, flag;
    if (!tzok) {               // contribution exactly zero everywhere
        bx0 = 1e30f; by0 = 1e30f; bx1 = -1e30f; by1 = -1e30f; flag = 0.0f;
    } else if (patho) {        // always evaluate
        bx0 = -1e30f; by0 = -1e30f; bx1 = 1e30f; by1 = 1e30f; flag = 2.0f;
    } else {
        // 0.3 px margin >= sqrt(BLUR)=0.0304 blur band + fp band
        bx0 = fminf(p0x, fminf(p1x, p2x)) - 0.3f;
        by0 = fminf(p0y, fminf(p1y, p2y)) - 0.3f;
        bx1 = fmaxf(p0x, fmaxf(p1x, p2x)) + 0.3f;
        by1 = fmaxf(p0y, fmaxf(p1y, p2y)) + 0.3f;
        flag = 1.0f;
    }

    int c = g / FCHUNK, f = g - c * FCHUNK;
    float4* ga = gA + (size_t)c * CH_EVAL;
    ga[4 * f + 0] = make_float4(p0x, p0y, e0x, e0y);
    ga[4 * f + 1] = make_float4(p1x, p1y, e1x, e1y);
    ga[4 * f + 2] = make_float4(p2x, p2y, e2x, e2y);
    ga[4 * f + 3] = make_float4(rd0, rd1, rd2, tzok ? 1.0f : 0.0f);

    float* gs = gS + (size_t)c * CH_SCAN_F;
    float sgn = (orient >= 0.0f) ? 1.0f : -1.0f;   // triangle side -> positive
    gs[0 * FCHUNK + f] = bx0;  gs[1 * FCHUNK + f] = by0;
    gs[2 * FCHUNK + f] = bx1;  gs[3 * FCHUNK + f] = by1;
    gs[4 * FCHUNK + f] = flag;
    gs[5 * FCHUNK + f] = p0x;  gs[6 * FCHUNK + f] = p1x;  gs[7 * FCHUNK + f] = p2x;
    gs[8 * FCHUNK + f] = p0y;  gs[9 * FCHUNK + f] = p1y;  gs[10 * FCHUNK + f] = p2y;
    gs[11 * FCHUNK + f] = sgn * e0x; gs[12 * FCHUNK + f] = sgn * e1x; gs[13 * FCHUNK + f] = sgn * e2x;
    gs[14 * FCHUNK + f] = sgn * e0y; gs[15 * FCHUNK + f] = sgn * e1y; gs[16 * FCHUNK + f] = sgn * e2y;
    gs[17 * FCHUNK + f] = rd0; gs[18 * FCHUNK + f] = rd1; gs[19 * FCHUNK + f] = rd2;
}

// One face evaluation, bitwise-matching the reference on the sign-test cliff
// (crosses), fast-math on the smooth parts (2e-2 slack).
__device__ __forceinline__ float eval_face(const float4* sf, int f,
                                           float px, float py)
{
    float4 r0v = sf[FREC * f + 0];   // uniform addr -> LDS broadcast
    float4 r1v = sf[FREC * f + 1];
    float4 r2v = sf[FREC * f + 2];
    float4 dv  = sf[FREC * f + 3];

    float a0x = px - r0v.x, a0y = py - r0v.y;
    float a1x = px - r1v.x, a1y = py - r1v.y;
    float a2x = px - r2v.x, a2y = py - r2v.y;

    float c0, c1, c2;
    {
#pragma clang fp contract(off)
        c0 = r0v.z * a0y - r0v.w * a0x;
        c1 = r1v.z * a1y - r1v.w * a1x;
        c2 = r2v.z * a2y - r2v.w * a2x;
    }
    bool pos = (c0 >= 0.0f) & (c1 >= 0.0f) & (c2 >= 0.0f);
    bool neg = (c0 <= 0.0f) & (c1 <= 0.0f) & (c2 <= 0.0f);

    float t0 = fminf(fmaxf((a0x * r0v.z + a0y * r0v.w) * dv.x, 0.0f), 1.0f);
    float t1 = fminf(fmaxf((a1x * r1v.z + a1y * r1v.w) * dv.y, 0.0f), 1.0f);
    float t2 = fminf(fmaxf((a2x * r2v.z + a2y * r2v.w) * dv.z, 0.0f), 1.0f);
    float u0x = a0x - t0 * r0v.z, u0y = a0y - t0 * r0v.w;
    float u1x = a1x - t1 * r1v.z, u1y = a1y - t1 * r1v.w;
    float u2x = a2x - t2 * r2v.z, u2y = a2y - t2 * r2v.w;
    float d20 = u0x * u0x + u0y * u0y;
    float d21 = u1x * u1x + u1y * u1y;
    float d22 = u2x * u2x + u2y * u2y;
    float d2m = fminf(d20, fminf(d21, d22));

    bool inside = pos | neg;
    float uu = (inside ? d2m : -d2m) * 1.0e4f;
    bool valid = (dv.w != 0.0f) & (inside | (d2m <= 9.2102404e-4f));
    float sp;
    if (uu > 16.0f) sp = uu;     // softplus(uu)=uu to <1.2e-7
    else sp = fmaxf(uu, 0.0f) + __logf(1.0f + __expf(-fabsf(uu)));
    return valid ? sp : 0.0f;
}

// Structure notes (R2/R4/R5/R6/R7 post-mortems):
//  - NO device-scope fences / global atomics in the hot path (R2 fence storm).
//  - Exclusive (tile,chunk) ownership -> plain store into ws partials (R5).
//  - Alpha-saturation early exit (all lanes <= -30 -> alpha bitwise 1.0f for
//    both ref and kernel) kills interior-tile stragglers (R6, -25us).
//  - SAT tile/triangle cull + 2-wide ILP eval (R7, -4us).
//  - R8: staging is a pure coalesced float4 copy of prep's records (450
//    float4/block); FCHUNK=50 -> single ballot round, halved serial tails.
__global__ __launch_bounds__(BLK) void sil_kernel(
    const float4* __restrict__ gA, const float* __restrict__ gS,
    float* __restrict__ ws)
{
    __shared__ float4 sf[CH_EVAL];       // 3200 B eval records
    __shared__ float4 sscan4[CH_SCAN_V]; // 4000 B scan SoA
    const float* ss = (const float*)sscan4;

    // ---- coalesced staging: 450 float4, 2 rounds of 256 ----
    {
        const float4* ga = gA + (size_t)blockIdx.y * CH_EVAL;
        const float4* gs4 = (const float4*)gS + (size_t)blockIdx.y * CH_SCAN_V;
        for (int i = threadIdx.x; i < CH_EVAL + CH_SCAN_V; i += BLK) {
            if (i < CH_EVAL) sf[i] = ga[i];
            else             sscan4[i - CH_EVAL] = gs4[i - CH_EVAL];
        }
    }
    __syncthreads();

    int wave = threadIdx.x >> 6, lane = threadIdx.x & 63;
    int tile = blockIdx.x * TPB + wave;
    if (tile >= NTILE) return;

    int ty = tile / TX_N, tx = tile - ty * TX_N;
    int col = tx * TW + (lane & 7);
    int row = ty * TH + (lane >> 3);
    bool live = col < WI;                  // x-tail tiles partially valid
    int q = row * WI + col;
    float px = (float)col + 0.5f;
    float py = (float)row + 0.5f;
    // wave-uniform 8x8 tile rect (pixel centers)
    float wx0 = (float)(tx * TW) + 0.5f, wx1 = (float)(tx * TW + TW - 1) + 0.5f;
    float wy0 = (float)(ty * TH) + 0.5f, wy1 = (float)(ty * TH + TH - 1) + 0.5f;

    // dead lanes start saturated so they never block the early-exit ballot
    float sum = live ? 0.0f : -1e30f;

    // ---- lane-parallel scan: FCHUNK=50 <= 64 -> one round ----
    bool ov = false;
    if (lane < FCHUNK) {
        int fl = lane;
        ov = !(ss[0 * FCHUNK + fl] > wx1 || ss[2 * FCHUNK + fl] < wx0 ||
               ss[1 * FCHUNK + fl] > wy1 || ss[3 * FCHUNK + fl] < wy0);
        if (ov && ss[4 * FCHUNK + fl] == 1.0f) {
            // SAT: rect separated from triangle by edge k's line with >0.3px
            // margin -> exactly zero contribution for the whole tile.
            // Cross affine in p: max over rect corners =
            // base + max(0,-7*Ey) + max(0,7*Ex).
            bool cull = false;
#pragma unroll
            for (int k = 0; k < 3; ++k) {
                float Ex = ss[(11 + k) * FCHUNK + fl];
                float Ey = ss[(14 + k) * FCHUNK + fl];
                float base = Ex * (wy0 - ss[(8 + k) * FCHUNK + fl])
                           - Ey * (wx0 - ss[(5 + k) * FCHUNK + fl]);
                float mx = base + fmaxf(0.0f, -7.0f * Ey)
                                + fmaxf(0.0f,  7.0f * Ex);
                cull |= (mx < 0.0f) & (mx * mx * ss[(17 + k) * FCHUNK + fl] > 0.09f);
            }
            ov = !cull;
        }
    }
    unsigned long long m = __ballot(ov);

    while (m) {
        // pop two bits; duplicate+mask the second when absent so both evals
        // sit in one basic block (independent chains -> ILP)
        int f0 = __ffsll((long long)m) - 1;
        m &= m - 1;
        bool has1 = (m != 0);
        int f1 = has1 ? (__ffsll((long long)m) - 1) : f0;
        if (has1) m &= m - 1;

        float s0 = eval_face(sf, f0, px, py);
        float s1 = eval_face(sf, f1, px, py);
        sum -= s0 + (has1 ? s1 : 0.0f);

        // alpha saturation: every lane <= -30 -> 1-exp(S) is bitwise 1.0f
        // for both ref and kernel; remaining faces can't change anything.
        if (__ballot(sum <= -30.0f) == 0xFFFFFFFFFFFFFFFFull) break;
    }
    // exclusive ownership of (chunk, pixel) -> plain coalesced store
    if (live) ws[(size_t)blockIdx.y * NPIX + q] = sum;
}

__global__ __launch_bounds__(BLK) void fin_kernel(
    const float* __restrict__ ws, const float* __restrict__ gt,
    float* __restrict__ out)
{
    __shared__ float wsum[BLK / 64];
    int q = blockIdx.x * BLK + threadIdx.x;
    float c = 0.0f;
    if (q < NPIX) {
        float s = 0.0f;
        for (int ch = 0; ch < NCHUNK; ++ch) s += ws[(size_t)ch * NPIX + q];
        float alpha = 1.0f - __expf(s);    // exp(very negative) -> 0 -> alpha=1
        out[1 + q] = alpha;
        c = fabsf(alpha - gt[q]);
    }
    for (int off = 32; off > 0; off >>= 1) c += __shfl_down(c, off, 64);
    if ((threadIdx.x & 63) == 0) wsum[threadIdx.x >> 6] = c;
    __syncthreads();
    if (threadIdx.x == 0) {
        float s = 0.0f;
        for (int w = 0; w < BLK / 64; ++w) s += wsum[w];
        atomicAdd(&out[0], s * (1.0f / (float)NPIX));   // out[0] zeroed by prep
    }
}

extern "C" void kernel_launch(void* const* d_in, const int* in_sizes, int n_in,
                              void* d_out, int out_size, void* d_ws, size_t ws_size,
                              hipStream_t stream)
{
    const float* verts = (const float*)d_in[0];
    const float* gt    = (const float*)d_in[1];
    const int*   faces = (const int*)d_in[2];
    float* out = (float*)d_out;          // out[0]=loss, out[1..]=sil (H*W)

    // workspace layout
    char* w = (char*)d_ws;
    float* ws = (float*)w;                                   // partials: 20*NPIX floats
    float4* gA = (float4*)(w + (size_t)NCHUNK * NPIX * 4);   // eval records: 1000*4 float4
    float* gS  = (float*)((char*)gA + (size_t)NF * FREC * 16); // scan SoA: 20000 floats

    prep_kernel<<<(NF + BLK - 1) / BLK, BLK, 0, stream>>>(verts, faces, out, gA, gS);

    dim3 sgrid(NBX, NCHUNK);             // 128 x 20 = 2560 blocks
    sil_kernel<<<sgrid, BLK, 0, stream>>>(gA, gS, ws);

    fin_kernel<<<(NPIX + BLK - 1) / BLK, BLK, 0, stream>>>(ws, gt, out);
}